// Round 1
// baseline (462.214 us; speedup 1.0000x reference)
//
#include <hip/hip_runtime.h>

// SNN with "swapped outputs" bug: stored state = spike (binary), forwarded
// value = membrane. Since reset = (spk_prev > 1) == 0 always, mem = cur + 0.9*spk_prev.
// With constant input current, every layer's spike pattern fixates:
//   mem0 const for t>=1, mem1 const for t>=2, mem2 (output) const for t>=3.
// So: GEMM0 (256x2048,K=1024) once; GEMM1 batched over {mem0(0), mem0(inf)} (M=512,K=2048);
// GEMM2 batched over {mem1(0), mem1(1), mem1(inf)} (M=768,K=2048); broadcast t>=3.
// All GEMMs accumulate in fp64 so spike threshold decisions match the numpy reference.

#define TILE 64
#define KT 16

__global__ __launch_bounds__(256) void gemm_bias_f64(
    const float* __restrict__ A,   // [M,K] row-major
    const float* __restrict__ W,   // [N,K] row-major (we compute A @ W^T)
    const float* __restrict__ bias,// [N]
    float* __restrict__ C,         // [M,N]
    int M, int N, int K)
{
    __shared__ double As[KT][TILE];
    __shared__ double Ws[KT][TILE];

    const int tid = threadIdx.x;           // 0..255
    const int tx = tid & 15;               // 0..15 -> 4 cols each
    const int ty = tid >> 4;               // 0..15 -> 4 rows each
    const int row0 = blockIdx.y * TILE;
    const int col0 = blockIdx.x * TILE;

    const int lrow = tid >> 2;             // 0..63
    const int lk4  = (tid & 3) << 2;       // 0,4,8,12

    const float* Ap = A + (size_t)(row0 + lrow) * K + lk4;
    const float* Wp = W + (size_t)(col0 + lrow) * K + lk4;

    double acc[4][4] = {};

    for (int k0 = 0; k0 < K; k0 += KT) {
        const float4 av = *reinterpret_cast<const float4*>(Ap + k0);
        const float4 wv = *reinterpret_cast<const float4*>(Wp + k0);
        __syncthreads();   // previous iteration's reads complete
        As[lk4 + 0][lrow] = (double)av.x;
        As[lk4 + 1][lrow] = (double)av.y;
        As[lk4 + 2][lrow] = (double)av.z;
        As[lk4 + 3][lrow] = (double)av.w;
        Ws[lk4 + 0][lrow] = (double)wv.x;
        Ws[lk4 + 1][lrow] = (double)wv.y;
        Ws[lk4 + 2][lrow] = (double)wv.z;
        Ws[lk4 + 3][lrow] = (double)wv.w;
        __syncthreads();
#pragma unroll
        for (int kk = 0; kk < KT; ++kk) {
            double a[4], w[4];
#pragma unroll
            for (int i = 0; i < 4; ++i) a[i] = As[kk][ty * 4 + i];
#pragma unroll
            for (int j = 0; j < 4; ++j) w[j] = Ws[kk][tx * 4 + j];
#pragma unroll
            for (int i = 0; i < 4; ++i)
#pragma unroll
                for (int j = 0; j < 4; ++j)
                    acc[i][j] = fma(a[i], w[j], acc[i][j]);
        }
    }

    const float* bp = bias + col0 + tx * 4;
    double b4[4];
#pragma unroll
    for (int j = 0; j < 4; ++j) b4[j] = (double)bp[j];

#pragma unroll
    for (int i = 0; i < 4; ++i) {
        float4 o;
        o.x = (float)(acc[i][0] + b4[0]);
        o.y = (float)(acc[i][1] + b4[1]);
        o.z = (float)(acc[i][2] + b4[2]);
        o.w = (float)(acc[i][3] + b4[3]);
        *reinterpret_cast<float4*>(
            &C[(size_t)(row0 + ty * 4 + i) * N + col0 + tx * 4]) = o;
    }
}

// mem0(inf) = cur0 + 0.9*[cur0 > 1]; input cur0 in lo half, write hi half.
__global__ __launch_bounds__(256) void lif0_kernel(float* __restrict__ a1, int n)
{
    int i = blockIdx.x * 256 + threadIdx.x;
    if (i < n) {
        float c = a1[i];
        a1[n + i] = c + ((c > 1.0f) ? 0.9f : 0.0f);
    }
}

// From cur1(0), cur1(inf) build mem1(0), mem1(1), mem1(inf).
__global__ __launch_bounds__(256) void lif1_kernel(const float* __restrict__ c1,
                                                   float* __restrict__ a2, int n)
{
    int i = blockIdx.x * 256 + threadIdx.x;
    if (i < n) {
        float c0   = c1[i];        // cur1 at t=0
        float cinf = c1[n + i];    // cur1 at t>=1
        float m0 = c0;                                   // mem1(0)
        bool  s0 = m0 > 1.0f;                            // s1(0)
        float m1 = cinf + (s0 ? 0.9f : 0.0f);            // mem1(1)
        bool  s1 = m1 > 1.0f;                            // s1(1) = s1(t>=1)
        float mi = cinf + (s1 ? 0.9f : 0.0f);            // mem1(t>=2)
        a2[i]         = m0;
        a2[n + i]     = m1;
        a2[2 * n + i] = mi;
    }
}

// Final layer + output broadcast. n = 256*1024.
__global__ __launch_bounds__(256) void lif2_kernel(const float* __restrict__ c2,
                                                   float* __restrict__ out, int n)
{
    int i = blockIdx.x * 256 + threadIdx.x;
    if (i < n) {
        float c0   = c2[i];          // cur2(0)
        float c1   = c2[n + i];      // cur2(1)
        float cinf = c2[2 * n + i];  // cur2(t>=2)
        float m0 = c0;                                 // out t=0
        bool  s0 = m0 > 1.0f;
        float m1 = c1 + (s0 ? 0.9f : 0.0f);            // out t=1
        bool  s1 = m1 > 1.0f;
        float m2 = cinf + (s1 ? 0.9f : 0.0f);          // out t=2
        bool  s2 = m2 > 1.0f;
        float m3 = cinf + (s2 ? 0.9f : 0.0f);          // out t>=3 (fixed point)
        out[i]         = m0;
        out[n + i]     = m1;
        out[2 * n + i] = m2;
#pragma unroll 1
        for (int t = 3; t < 100; ++t)
            out[(size_t)t * n + i] = m3;
    }
}

extern "C" void kernel_launch(void* const* d_in, const int* in_sizes, int n_in,
                              void* d_out, int out_size, void* d_ws, size_t ws_size,
                              hipStream_t stream)
{
    const float* x  = (const float*)d_in[0];  // [256,1024]
    const float* W0 = (const float*)d_in[1];  // [2048,1024]
    const float* b0 = (const float*)d_in[2];  // [2048]
    const float* W1 = (const float*)d_in[3];  // [2048,2048]
    const float* b1 = (const float*)d_in[4];  // [2048]
    const float* W2 = (const float*)d_in[5];  // [1024,2048]
    const float* b2 = (const float*)d_in[6];  // [1024]
    float* out = (float*)d_out;
    float* ws  = (float*)d_ws;

    const int B = 256, H = 2048, DOUT = 1024, DIN = 1024;
    const int nBH = B * H;        // 524288
    const int nBO = B * DOUT;     // 262144

    // ws layout (floats): A1 [512,2048] @0 ; C1 [512,2048] @1048576 ;
    // A2 [768,2048] @2097152 ; C2 [768,1024] reuses A1's slot @0 (A1 dead by then).
    float* A1 = ws;
    float* C1 = ws + 1048576;
    float* A2 = ws + 2097152;
    float* C2 = ws;

    dim3 blk(256);

    // GEMM0: cur0 = x @ W0^T + b0 -> rows 0..255 of A1
    gemm_bias_f64<<<dim3(H / TILE, B / TILE), blk, 0, stream>>>(x, W0, b0, A1, B, H, DIN);
    // mem0(inf) -> rows 256..511 of A1
    lif0_kernel<<<dim3(nBH / 256), blk, 0, stream>>>(A1, nBH);
    // GEMM1 batched: [cur1(0); cur1(inf)] = [mem0(0); mem0(inf)] @ W1^T + b1
    gemm_bias_f64<<<dim3(H / TILE, (2 * B) / TILE), blk, 0, stream>>>(A1, W1, b1, C1, 2 * B, H, H);
    // mem1(0), mem1(1), mem1(inf)
    lif1_kernel<<<dim3(nBH / 256), blk, 0, stream>>>(C1, A2, nBH);
    // GEMM2 batched: 3 currents for layer 2
    gemm_bias_f64<<<dim3(DOUT / TILE, (3 * B) / TILE), blk, 0, stream>>>(A2, W2, b2, C2, 3 * B, DOUT, H);
    // layer-2 LIF + broadcast t>=3
    lif2_kernel<<<dim3(nBO / 256), blk, 0, stream>>>(C2, out, nBO);
}